// Round 9
// baseline (531.806 us; speedup 1.0000x reference)
//
#include <hip/hip_runtime.h>

// NNConvCritic on MI355X (gfx950).
// R9: occupancy x2.5 + VALU diet. Edge: 128-thread blocks = 2 autonomous
// waves (barrier-free loop, shared gacc), grid 3072 -> 6 waves/SIMD
// (launch_bounds(128,6): VGPR cap 84 > 68 used, no spill). Edge->graph
// resolution: 2 loads + 4 ds_bpermute (__shfl) instead of 8 scalar gathers.
// kq partners mapped to same XCD for ea L2 reuse.
// Pipeline: memset -> setup -> mid -> edge -> critic.

#define E_EDGES   800000
#define N_NODES   50000
#define G_GRAPHS  64
#define EDGE_BLOCKS 3072    // x2 waves = 6144 streams-of-waves
#define NGROUPS   50000     // E/16
#define GSTRIDE   1536      // group streams (6144/4)
#define NSUP      256       // super-slices for the int flush
#define STAT_GRID 512
#define QSCALE    131072.0f // 2^17
#define QINV      (1.0f / 131072.0f)

typedef _Float16 f16x2 __attribute__((ext_vector_type(2)));
typedef _Float16 f16x8 __attribute__((ext_vector_type(8)));
typedef __fp16   fp16x2 __attribute__((ext_vector_type(2)));
typedef float    f32x4 __attribute__((ext_vector_type(4)));
typedef unsigned u32x4 __attribute__((ext_vector_type(4)));

union H2U { f16x2 h; unsigned u; };
union F8U { f16x8 v; f16x2 h2[4]; u32x4 u4; };

__device__ __forceinline__ f16x2 pkrtz(float a, float b) {
  fp16x2 r = __builtin_amdgcn_cvt_pkrtz(a, b);
  return __builtin_bit_cast(f16x2, r);
}

// ---------------------------------------------------------------------------
// setup: blocks [0,512) stats | [512,582) prep | [582,...) xconv.
// ---------------------------------------------------------------------------
__global__ __launch_bounds__(256) void setup_kernel(
    const float* __restrict__ W2, const float* __restrict__ b2,
    const float* __restrict__ W1, const float* __restrict__ x,
    const float* __restrict__ ea, unsigned* __restrict__ Bbuf,
    unsigned* __restrict__ Bw1, unsigned* __restrict__ xh,
    float* __restrict__ gstatsT)
{
  __shared__ float red[4][272];
  const int b = blockIdx.x, tid = threadIdx.x;
  if (b < STAT_GRID) {
    int lane = tid & 63, wave = tid >> 6;
    int nl = lane & 15, q = lane >> 4;
    int gw = b * 4 + wave;
    f32x4 acc = (f32x4){0.f, 0.f, 0.f, 0.f};
    float ms = 0.f;
    for (int c0 = gw; c0 < E_EDGES / 32; c0 += STAT_GRID * 4) {
      const float* p = ea + (size_t)(c0 * 32 + q * 8) * 16 + nl;
      float v0 = p[0],  v1 = p[16], v2 = p[32], v3 = p[48];
      float v4 = p[64], v5 = p[80], v6 = p[96], v7 = p[112];
      ms += (v0 + v1) + (v2 + v3) + (v4 + v5) + (v6 + v7);
      F8U av;
      av.h2[0] = pkrtz(v0, v1); av.h2[1] = pkrtz(v2, v3);
      av.h2[2] = pkrtz(v4, v5); av.h2[3] = pkrtz(v6, v7);
      acc = __builtin_amdgcn_mfma_f32_16x16x32_f16(av.v, av.v, acc, 0, 0, 0);
    }
    ms += __shfl_xor(ms, 16, 64);
    ms += __shfl_xor(ms, 32, 64);
#pragma unroll
    for (int r = 0; r < 4; ++r) red[wave][(q * 4 + r) * 16 + nl] = acc[r];
    if (q == 0) red[wave][256 + nl] = ms;
    __syncthreads();
    for (int v = tid; v < 272; v += 256)
      gstatsT[(size_t)v * STAT_GRID + b] =
          red[0][v] + red[1][v] + red[2][v] + red[3][v];
  } else if (b < STAT_GRID + 70) {
    int idx = (b - STAT_GRID) * 256 + tid;  // [0, 17920) = 16896 + 1024
    if (idx < 33 * 512) {
      int r = idx & 3, lane = (idx >> 2) & 63, nt = (idx >> 8) & 1,
          s = idx >> 9;
      int q = lane >> 4, nl = lane & 15, n = nt * 16 + nl;
      float v0 = 0.f, v1 = 0.f;
      if (n < 20) {
        if (s < 32) {
          int K0 = s * 32 + q * 8 + 2 * r;
          v0 = W2[(K0 >> 4) * 320 + (K0 & 15) * 20 + n];
          v1 = W2[((K0 + 1) >> 4) * 320 + ((K0 + 1) & 15) * 20 + n];
        } else if (q < 2) {
          int i0 = q * 8 + 2 * r;
          v0 = b2[i0 * 20 + n];
          v1 = b2[(i0 + 1) * 20 + n];
        }
      }
      H2U pk; pk.h = pkrtz(v0, v1);
      Bbuf[idx] = pk.u;
    } else {
      int idx2 = idx - 33 * 512;  // [0,1024)
      int r = idx2 & 3, lane = (idx2 >> 2) & 63, nt = idx2 >> 8;
      int q = lane >> 4, nl = lane & 15, n = nt * 16 + nl;
      int k0 = q * 8 + 2 * r;
      float v0 = (k0 < 16)     ? W1[k0 * 64 + n]       : 0.f;
      float v1 = (k0 + 1 < 16) ? W1[(k0 + 1) * 64 + n] : 0.f;
      H2U pk; pk.h = pkrtz(v0, v1);
      Bw1[idx2] = pk.u;
    }
  } else {
    int i = (b - STAT_GRID - 70) * 256 + tid;
    if (i < N_NODES * 8) {
      H2U pk; pk.h = pkrtz(x[2 * i], x[2 * i + 1]);
      xh[i] = pk.u;
    }
  }
}

// ---------------------------------------------------------------------------
// mid: block 64 = stats reduce + BN scale/shift; blocks 0..63 = sumx/cnt.
// ---------------------------------------------------------------------------
__global__ __launch_bounds__(256) void mid_kernel(
    const float* __restrict__ gstatsT, const float* __restrict__ W1,
    const float* __restrict__ b1, const float* __restrict__ gamma,
    const float* __restrict__ beta, const float* __restrict__ x,
    const int* __restrict__ batch, float* __restrict__ sc,
    float* __restrict__ sh, float* __restrict__ sumx,
    float* __restrict__ cntf)
{
  const int t = threadIdx.x;
  if (blockIdx.x == G_GRAPHS) {
    __shared__ float S[272];
    for (int v = t; v < 272; v += 256) {
      const float* p = gstatsT + (size_t)v * STAT_GRID;
      float s0 = 0.f, s1 = 0.f, s2 = 0.f, s3 = 0.f;
      for (int bb = 0; bb < STAT_GRID; bb += 4) {
        s0 += p[bb]; s1 += p[bb + 1]; s2 += p[bb + 2]; s3 += p[bb + 3];
      }
      S[v] = (s0 + s1) + (s2 + s3);
    }
    __syncthreads();
    if (t < 64) {
      float w[16];
#pragma unroll
      for (int j = 0; j < 16; ++j) w[j] = W1[j * 64 + t];
      const float invE = 1.0f / (float)E_EDGES;
      float mw = 0.f;
#pragma unroll
      for (int j = 0; j < 16; ++j) mw += S[256 + j] * w[j];
      mw *= invE;
      float qf = 0.f;
      for (int j = 0; j < 16; ++j) {
        float tt = 0.f;
#pragma unroll
        for (int j2 = 0; j2 < 16; ++j2) tt += S[j * 16 + j2] * w[j2];
        qf += w[j] * tt;
      }
      qf *= invE;
      float b = b1[t];
      float meanH = mw + b;
      float eh2 = qf + 2.f * b * mw + b * b;
      float var = eh2 - meanH * meanH;
      float s = gamma[t] * rsqrtf(var + 1e-5f);
      sc[t] = s;
      sh[t] = beta[t] + (b - meanH) * s;
    }
  } else {
    int g = blockIdx.x;
    __shared__ int se[2];
    if (t < 2) {
      int key = g + t;
      int lo = 0, hi = N_NODES;
      while (lo < hi) {
        int mid = (lo + hi) >> 1;
        if (batch[mid] < key) lo = mid + 1; else hi = mid;
      }
      se[t] = lo;
    }
    __syncthreads();
    int start = se[0], end = se[1];
    int c = t & 15, rr = t >> 4;
    float s = 0.f;
    for (int n = start + rr; n < end; n += 16) s += x[(size_t)n * 16 + c];
    __shared__ float red[256];
    red[t] = s;
    __syncthreads();
#pragma unroll
    for (int st = 128; st >= 16; st >>= 1) {
      if (t < st) red[t] += red[t + st];
      __syncthreads();
    }
    if (t < 16) sumx[g * 16 + t] = red[t];
    if (t == 0) cntf[g] = (float)(end - start);
  }
}

// ---------------------------------------------------------------------------
// edge_kernel: 128 threads = 2 autonomous waves (no barriers in loop).
// Wave-stream ws handles K-quarter kq=(ws>>4)&3 of groups sgroup,
// sgroup+1536, ... (kq partners differ by ws 16/32/48 -> blockIdx 8/16/24 ->
// same XCD -> ea re-reads hit L2/L3). Per-wave private hh; block-shared gacc
// (native ds_add_u32 fixed-point). Edge->graph via 2 loads + 4 __shfl.
// Flush: global int atomics into 256 super-slices.
// ---------------------------------------------------------------------------
__global__ __launch_bounds__(128, 6) void edge_kernel(
    const unsigned* __restrict__ xh, const float* __restrict__ ea,
    const int* __restrict__ ei, const int* __restrict__ batch,
    const float* __restrict__ sc, const float* __restrict__ sh,
    const unsigned* __restrict__ Bbuf, const unsigned* __restrict__ Bw1v,
    int* __restrict__ gpartI)
{
  __shared__ unsigned hh[2][320];  // per-wave [channel 16][m 16 pad 20]
  __shared__ int gacc[1280];       // block-shared per-graph fixed-point sums
  const int tid = threadIdx.x;
  const int lane = tid & 63, wv = tid >> 6;
  const int nl = lane & 15, q = lane >> 4;
  const int ws = blockIdx.x * 2 + wv;
  const int kq = (ws >> 4) & 3;
  const int sgroup = ((ws >> 6) << 4) | (ws & 15);   // [0, 1536)
  const int* srcp = ei;
  const int* dstp = ei + E_EDGES;

  for (int v = tid; v < 1280; v += 128) gacc[v] = 0;

  // persistent B fragments (this wave's K-quarter)
  F8U bb[8][2];
#pragma unroll
  for (int sl = 0; sl < 8; ++sl)
#pragma unroll
    for (int nt = 0; nt < 2; ++nt)
      bb[sl][nt].u4 =
          ((const u32x4*)Bbuf)[((kq * 8 + sl) * 2 + nt) * 64 + lane];
  F8U bx[2];
  if (kq == 3) {
    bx[0].u4 = ((const u32x4*)Bbuf)[64 * 64 + lane];
    bx[1].u4 = ((const u32x4*)Bbuf)[65 * 64 + lane];
  } else {
    bx[0].u4 = (u32x4){0u, 0u, 0u, 0u};
    bx[1].u4 = (u32x4){0u, 0u, 0u, 0u};
  }
  F8U bw1; bw1.u4 = ((const u32x4*)Bw1v)[kq * 64 + lane];
  const float scv = sc[kq * 16 + nl];
  const float shv = sh[kq * 16 + nl];
  unsigned* myhh = hh[wv];
  const int hrb = (q >> 1) * 20 + nl;   // read: c = 2sl + (q>>1), m = nl
  const int qh = q & 1;
  __syncthreads();  // gacc init visible to both waves

  // ---- prologue: loads for first group ----
  int g = sgroup;
  f32x4 eaA = (f32x4){0.f,0.f,0.f,0.f}, eaB = eaA;
  u32x4 xp = (u32x4){0u,0u,0u,0u};
  int ge = 0;
  {
    int base = g * 16;
    if (q < 2) {
      const float* p = ea + (size_t)(base + nl) * 16 + q * 8;
      eaA = *(const f32x4*)p;
      eaB = *(const f32x4*)(p + 4);
    }
    int src = srcp[base + nl];
    xp = ((const u32x4*)xh)[src * 2 + qh];
    ge = batch[dstp[base + nl]];   // lane nl holds graph of edge nl
  }

  while (g < NGROUPS) {
    const int gn = g + GSTRIDE;

    // ---- h-stage: 16 edges x this wave's 16 channels (1 MFMA) ----
    {
      F8U aEA;
      if (q < 2) {
        aEA.h2[0] = pkrtz(eaA[0], eaA[1]); aEA.h2[1] = pkrtz(eaA[2], eaA[3]);
        aEA.h2[2] = pkrtz(eaB[0], eaB[1]); aEA.h2[3] = pkrtz(eaB[2], eaB[3]);
      } else {
        aEA.u4 = (u32x4){0u, 0u, 0u, 0u};
      }
      f32x4 hD = __builtin_amdgcn_mfma_f32_16x16x32_f16(
          aEA.v, bw1.v, (f32x4){0.f, 0.f, 0.f, 0.f}, 0, 0, 0);
#pragma unroll
      for (int r = 0; r < 4; ++r) {
        float h = fmaxf(hD[r] * scv + shv, 0.f);
        H2U pk; pk.h = pkrtz(h, h);     // packed-duplicated
        myhh[nl * 20 + q * 4 + r] = pk.u;  // [c=nl][m=q*4+r]
      }
    }
    F8U xcur; xcur.u4 = xp;
    // edge->graph for this wave's 4 C-rows (ds_bpermute, LDS pipe)
    int gq0 = __shfl(ge, q * 4 + 0, 64);
    int gq1 = __shfl(ge, q * 4 + 1, 64);
    int gq2 = __shfl(ge, q * 4 + 2, 64);
    int gq3 = __shfl(ge, q * 4 + 3, 64);

    // ---- prefetch next group (overlaps K-loop; wave-local vmcnt) ----
    f32x4 eaAn = (f32x4){0.f,0.f,0.f,0.f}, eaBn = eaAn;
    u32x4 xpn = (u32x4){0u,0u,0u,0u};
    int gen = 0;
    if (gn < NGROUPS) {
      int base = gn * 16;
      if (q < 2) {
        const float* p = ea + (size_t)(base + nl) * 16 + q * 8;
        eaAn = *(const f32x4*)p;
        eaBn = *(const f32x4*)(p + 4);
      }
      int src = srcp[base + nl];
      xpn = ((const u32x4*)xh)[src * 2 + qh];
      gen = batch[dstp[base + nl]];
    }

    // ---- K-loop: A[m][k] = h[m][c] * x[m][i], 8 steps x 2 N-tiles ----
    f32x4 acc0 = (f32x4){0.f, 0.f, 0.f, 0.f};
    f32x4 acc1 = (f32x4){0.f, 0.f, 0.f, 0.f};
#pragma unroll
    for (int sl = 0; sl < 8; ++sl) {
      H2U hu; hu.u = myhh[hrb + sl * 40];
      F8U av;
      av.h2[0] = hu.h * xcur.h2[0];
      av.h2[1] = hu.h * xcur.h2[1];
      av.h2[2] = hu.h * xcur.h2[2];
      av.h2[3] = hu.h * xcur.h2[3];
      acc0 = __builtin_amdgcn_mfma_f32_16x16x32_f16(av.v, bb[sl][0].v, acc0,
                                                    0, 0, 0);
      acc1 = __builtin_amdgcn_mfma_f32_16x16x32_f16(av.v, bb[sl][1].v, acc1,
                                                    0, 0, 0);
    }
    if (kq == 3) {   // b2 extra K-step: A = x (coefficient-1 trick)
      F8U av;
      if (q < 2) av = xcur;
      else       av.u4 = (u32x4){0u, 0u, 0u, 0u};
      acc0 = __builtin_amdgcn_mfma_f32_16x16x32_f16(av.v, bx[0].v, acc0,
                                                    0, 0, 0);
      acc1 = __builtin_amdgcn_mfma_f32_16x16x32_f16(av.v, bx[1].v, acc1,
                                                    0, 0, 0);
    }

    // ---- fixed-point partials into block-shared gacc (ds_add_u32) ----
    {
      int gi;
      gi = gq0 * 20;
      atomicAdd(&gacc[gi + nl], __float2int_rn(acc0[0] * QSCALE));
      if (nl < 4) atomicAdd(&gacc[gi + 16 + nl], __float2int_rn(acc1[0] * QSCALE));
      gi = gq1 * 20;
      atomicAdd(&gacc[gi + nl], __float2int_rn(acc0[1] * QSCALE));
      if (nl < 4) atomicAdd(&gacc[gi + 16 + nl], __float2int_rn(acc1[1] * QSCALE));
      gi = gq2 * 20;
      atomicAdd(&gacc[gi + nl], __float2int_rn(acc0[2] * QSCALE));
      if (nl < 4) atomicAdd(&gacc[gi + 16 + nl], __float2int_rn(acc1[2] * QSCALE));
      gi = gq3 * 20;
      atomicAdd(&gacc[gi + nl], __float2int_rn(acc0[3] * QSCALE));
      if (nl < 4) atomicAdd(&gacc[gi + 16 + nl], __float2int_rn(acc1[3] * QSCALE));
    }

    // rotate prefetch -> current
    g = gn;
    eaA = eaAn; eaB = eaBn; xp = xpn; ge = gen;
  }

  // ---- flush: global int atomics into super-slice (12 blocks/slice) ----
  __syncthreads();  // both waves' gacc contributions complete
  const int ssup = blockIdx.x & (NSUP - 1);
  for (int v = tid; v < 1280; v += 128) {
    int gg = v / 20, o = v - gg * 20;
    atomicAdd(&gpartI[(gg * NSUP + ssup) * 20 + o], gacc[v]);
  }
}

// ---------------------------------------------------------------------------
// critic: block per graph. Exact int reduce of 256 super-slices; pooled =
// (msgsum + sumx@root_w + cnt*bias)/max(cnt,1); 2-layer MLP.
// ---------------------------------------------------------------------------
__global__ __launch_bounds__(256) void critic_kernel(
    const int* __restrict__ gpartI, const float* __restrict__ sumx,
    const float* __restrict__ cntf, const float* __restrict__ root_w,
    const float* __restrict__ bias, const float* __restrict__ a,
    const float* __restrict__ Wc1, const float* __restrict__ bc1,
    const float* __restrict__ Wc2, const float* __restrict__ bc2,
    float* __restrict__ out)
{
  int g = blockIdx.x, t = threadIdx.x;
  __shared__ int part[240];
  __shared__ float pooled[20];
  if (t < 240) {
    int col = t % 20, r = t / 20;  // 12 slice groups
    int s = 0;
    const int* gp = gpartI + (size_t)g * NSUP * 20;
    for (int sl = r; sl < NSUP; sl += 12) s += gp[sl * 20 + col];
    part[t] = s;
  }
  __syncthreads();
  if (t < 20) {
    int si = 0;
#pragma unroll
    for (int r = 0; r < 12; ++r) si += part[r * 20 + t];
    float s = (float)si * QINV;
    float cnt = cntf[g];
    float base = bias[t] * cnt;
#pragma unroll
    for (int i = 0; i < 16; ++i) base += sumx[g * 16 + i] * root_w[i * 20 + t];
    pooled[t] = (s + base) / fmaxf(cnt, 1.f);
  }
  __syncthreads();
  float z = bc1[t];
#pragma unroll
  for (int j = 0; j < 20; ++j) z += pooled[j] * Wc1[j * 256 + t];
#pragma unroll
  for (int j = 0; j < 8; ++j) z += a[g * 8 + j] * Wc1[(20 + j) * 256 + t];
  z = fmaxf(z, 0.f);
  float pr = z * Wc2[t];
#pragma unroll
  for (int off = 32; off >= 1; off >>= 1) pr += __shfl_down(pr, off, 64);
  __shared__ float red[4];
  if ((t & 63) == 0) red[t >> 6] = pr;
  __syncthreads();
  if (t == 0) out[g] = red[0] + red[1] + red[2] + red[3] + bc2[0];
}

// ---------------------------------------------------------------------------
extern "C" void kernel_launch(void* const* d_in, const int* in_sizes, int n_in,
                              void* d_out, int out_size, void* d_ws,
                              size_t ws_size, hipStream_t stream) {
  const float* x         = (const float*)d_in[0];
  const float* edge_attr = (const float*)d_in[1];
  const float* a         = (const float*)d_in[2];
  const int*   ei        = (const int*)d_in[3];
  const int*   batch     = (const int*)d_in[4];
  const float* W1        = (const float*)d_in[5];
  const float* b1        = (const float*)d_in[6];
  const float* gamma     = (const float*)d_in[7];
  const float* beta      = (const float*)d_in[8];
  const float* W2        = (const float*)d_in[9];
  const float* b2        = (const float*)d_in[10];
  const float* root_w    = (const float*)d_in[11];
  const float* bias      = (const float*)d_in[12];
  const float* Wc1       = (const float*)d_in[13];
  const float* bc1       = (const float*)d_in[14];
  const float* Wc2       = (const float*)d_in[15];
  const float* bc2       = (const float*)d_in[16];
  float* out = (float*)d_out;

  // ws layout (floats) — gpartI zeroed via memset, rest fully written
  float* wsf     = (float*)d_ws;
  float* sc      = wsf;                 // 64
  float* sh      = wsf + 64;            // 64
  float* sumx    = wsf + 128;           // 1024
  float* cntf    = wsf + 1152;          // 64
  unsigned* Bw1  = (unsigned*)(wsf + 1216);   // 1024 u32
  unsigned* Bbuf = (unsigned*)(wsf + 2240);   // 16896 u32
  float* gstatsT = wsf + 19136;         // 272*512 = 139264
  unsigned* xhp  = (unsigned*)(wsf + 158400); // N*8 = 400000 u32
  int* gpartI    = (int*)(wsf + 558400);      // 64*256*20 = 327680 ints

  (void)hipMemsetAsync(gpartI, 0, (size_t)G_GRAPHS * NSUP * 20 * sizeof(int),
                       stream);

  const int XCONV_BLOCKS = (N_NODES * 8 + 255) / 256;  // 1563
  setup_kernel<<<STAT_GRID + 70 + XCONV_BLOCKS, 256, 0, stream>>>(
      W2, b2, W1, x, edge_attr, Bbuf, Bw1, xhp, gstatsT);
  mid_kernel<<<G_GRAPHS + 1, 256, 0, stream>>>(gstatsT, W1, b1, gamma, beta,
                                               x, batch, sc, sh, sumx, cntf);
  edge_kernel<<<EDGE_BLOCKS, 128, 0, stream>>>(xhp, edge_attr, ei, batch, sc,
                                               sh, Bbuf, Bw1, gpartI);
  critic_kernel<<<G_GRAPHS, 256, 0, stream>>>(gpartI, sumx, cntf, root_w,
                                              bias, a, Wc1, bc1, Wc2, bc2,
                                              out);
}

// Round 10
// 251.134 us; speedup vs baseline: 2.1176x; 2.1176x over previous
//
#include <hip/hip_runtime.h>

// NNConvCritic on MI355X (gfx950).
// R10: R8's verified no-spill edge kernel (single-wave blocks, (64,3),
// VGPR 68) with grid 3072->6144 (24 blocks/CU: LDS 6656x24=159.7KB fits,
// 6 waves/SIMD x 68 VGPR = 408<=512 fits) + edge->graph via 2 loads +
// 4 __shfl (R9's VALU diet, untested there due to spill).
// LESSON (R6, R9): launch_bounds must never price VGPR budget below the
// ~68-reg live set (64 = persistent B-table) -> scratch spill, 10x traffic.
// Pipeline: memset -> setup -> mid -> edge -> critic.

#define E_EDGES   800000
#define N_NODES   50000
#define G_GRAPHS  64
#define EDGE_GRID 6144      // single-wave blocks; 24/CU
#define NGROUPS   50000     // E/16
#define GSTRIDE   1536      // group streams (6144/4)
#define NSUP      256       // super-slices for the int flush
#define STAT_GRID 512
#define QSCALE    131072.0f // 2^17
#define QINV      (1.0f / 131072.0f)

typedef _Float16 f16x2 __attribute__((ext_vector_type(2)));
typedef _Float16 f16x8 __attribute__((ext_vector_type(8)));
typedef __fp16   fp16x2 __attribute__((ext_vector_type(2)));
typedef float    f32x4 __attribute__((ext_vector_type(4)));
typedef unsigned u32x4 __attribute__((ext_vector_type(4)));

union H2U { f16x2 h; unsigned u; };
union F8U { f16x8 v; f16x2 h2[4]; u32x4 u4; };

__device__ __forceinline__ f16x2 pkrtz(float a, float b) {
  fp16x2 r = __builtin_amdgcn_cvt_pkrtz(a, b);
  return __builtin_bit_cast(f16x2, r);
}

// ---------------------------------------------------------------------------
// setup: blocks [0,512) stats | [512,582) prep | [582,...) xconv.
// ---------------------------------------------------------------------------
__global__ __launch_bounds__(256) void setup_kernel(
    const float* __restrict__ W2, const float* __restrict__ b2,
    const float* __restrict__ W1, const float* __restrict__ x,
    const float* __restrict__ ea, unsigned* __restrict__ Bbuf,
    unsigned* __restrict__ Bw1, unsigned* __restrict__ xh,
    float* __restrict__ gstatsT)
{
  __shared__ float red[4][272];
  const int b = blockIdx.x, tid = threadIdx.x;
  if (b < STAT_GRID) {
    int lane = tid & 63, wave = tid >> 6;
    int nl = lane & 15, q = lane >> 4;
    int gw = b * 4 + wave;
    f32x4 acc = (f32x4){0.f, 0.f, 0.f, 0.f};
    float ms = 0.f;
    for (int c0 = gw; c0 < E_EDGES / 32; c0 += STAT_GRID * 4) {
      const float* p = ea + (size_t)(c0 * 32 + q * 8) * 16 + nl;
      float v0 = p[0],  v1 = p[16], v2 = p[32], v3 = p[48];
      float v4 = p[64], v5 = p[80], v6 = p[96], v7 = p[112];
      ms += (v0 + v1) + (v2 + v3) + (v4 + v5) + (v6 + v7);
      F8U av;
      av.h2[0] = pkrtz(v0, v1); av.h2[1] = pkrtz(v2, v3);
      av.h2[2] = pkrtz(v4, v5); av.h2[3] = pkrtz(v6, v7);
      acc = __builtin_amdgcn_mfma_f32_16x16x32_f16(av.v, av.v, acc, 0, 0, 0);
    }
    ms += __shfl_xor(ms, 16, 64);
    ms += __shfl_xor(ms, 32, 64);
#pragma unroll
    for (int r = 0; r < 4; ++r) red[wave][(q * 4 + r) * 16 + nl] = acc[r];
    if (q == 0) red[wave][256 + nl] = ms;
    __syncthreads();
    for (int v = tid; v < 272; v += 256)
      gstatsT[(size_t)v * STAT_GRID + b] =
          red[0][v] + red[1][v] + red[2][v] + red[3][v];
  } else if (b < STAT_GRID + 70) {
    int idx = (b - STAT_GRID) * 256 + tid;  // [0, 17920) = 16896 + 1024
    if (idx < 33 * 512) {
      int r = idx & 3, lane = (idx >> 2) & 63, nt = (idx >> 8) & 1,
          s = idx >> 9;
      int q = lane >> 4, nl = lane & 15, n = nt * 16 + nl;
      float v0 = 0.f, v1 = 0.f;
      if (n < 20) {
        if (s < 32) {
          int K0 = s * 32 + q * 8 + 2 * r;
          v0 = W2[(K0 >> 4) * 320 + (K0 & 15) * 20 + n];
          v1 = W2[((K0 + 1) >> 4) * 320 + ((K0 + 1) & 15) * 20 + n];
        } else if (q < 2) {
          int i0 = q * 8 + 2 * r;
          v0 = b2[i0 * 20 + n];
          v1 = b2[(i0 + 1) * 20 + n];
        }
      }
      H2U pk; pk.h = pkrtz(v0, v1);
      Bbuf[idx] = pk.u;
    } else {
      int idx2 = idx - 33 * 512;  // [0,1024)
      int r = idx2 & 3, lane = (idx2 >> 2) & 63, nt = idx2 >> 8;
      int q = lane >> 4, nl = lane & 15, n = nt * 16 + nl;
      int k0 = q * 8 + 2 * r;
      float v0 = (k0 < 16)     ? W1[k0 * 64 + n]       : 0.f;
      float v1 = (k0 + 1 < 16) ? W1[(k0 + 1) * 64 + n] : 0.f;
      H2U pk; pk.h = pkrtz(v0, v1);
      Bw1[idx2] = pk.u;
    }
  } else {
    int i = (b - STAT_GRID - 70) * 256 + tid;
    if (i < N_NODES * 8) {
      H2U pk; pk.h = pkrtz(x[2 * i], x[2 * i + 1]);
      xh[i] = pk.u;
    }
  }
}

// ---------------------------------------------------------------------------
// mid: block 64 = stats reduce + BN scale/shift; blocks 0..63 = sumx/cnt.
// ---------------------------------------------------------------------------
__global__ __launch_bounds__(256) void mid_kernel(
    const float* __restrict__ gstatsT, const float* __restrict__ W1,
    const float* __restrict__ b1, const float* __restrict__ gamma,
    const float* __restrict__ beta, const float* __restrict__ x,
    const int* __restrict__ batch, float* __restrict__ sc,
    float* __restrict__ sh, float* __restrict__ sumx,
    float* __restrict__ cntf)
{
  const int t = threadIdx.x;
  if (blockIdx.x == G_GRAPHS) {
    __shared__ float S[272];
    for (int v = t; v < 272; v += 256) {
      const float* p = gstatsT + (size_t)v * STAT_GRID;
      float s0 = 0.f, s1 = 0.f, s2 = 0.f, s3 = 0.f;
      for (int bb = 0; bb < STAT_GRID; bb += 4) {
        s0 += p[bb]; s1 += p[bb + 1]; s2 += p[bb + 2]; s3 += p[bb + 3];
      }
      S[v] = (s0 + s1) + (s2 + s3);
    }
    __syncthreads();
    if (t < 64) {
      float w[16];
#pragma unroll
      for (int j = 0; j < 16; ++j) w[j] = W1[j * 64 + t];
      const float invE = 1.0f / (float)E_EDGES;
      float mw = 0.f;
#pragma unroll
      for (int j = 0; j < 16; ++j) mw += S[256 + j] * w[j];
      mw *= invE;
      float qf = 0.f;
      for (int j = 0; j < 16; ++j) {
        float tt = 0.f;
#pragma unroll
        for (int j2 = 0; j2 < 16; ++j2) tt += S[j * 16 + j2] * w[j2];
        qf += w[j] * tt;
      }
      qf *= invE;
      float b = b1[t];
      float meanH = mw + b;
      float eh2 = qf + 2.f * b * mw + b * b;
      float var = eh2 - meanH * meanH;
      float s = gamma[t] * rsqrtf(var + 1e-5f);
      sc[t] = s;
      sh[t] = beta[t] + (b - meanH) * s;
    }
  } else {
    int g = blockIdx.x;
    __shared__ int se[2];
    if (t < 2) {
      int key = g + t;
      int lo = 0, hi = N_NODES;
      while (lo < hi) {
        int mid = (lo + hi) >> 1;
        if (batch[mid] < key) lo = mid + 1; else hi = mid;
      }
      se[t] = lo;
    }
    __syncthreads();
    int start = se[0], end = se[1];
    int c = t & 15, rr = t >> 4;
    float s = 0.f;
    for (int n = start + rr; n < end; n += 16) s += x[(size_t)n * 16 + c];
    __shared__ float red[256];
    red[t] = s;
    __syncthreads();
#pragma unroll
    for (int st = 128; st >= 16; st >>= 1) {
      if (t < st) red[t] += red[t + st];
      __syncthreads();
    }
    if (t < 16) sumx[g * 16 + t] = red[t];
    if (t == 0) cntf[g] = (float)(end - start);
  }
}

// ---------------------------------------------------------------------------
// edge_kernel: one wave per block, barrier-free (R8 structure, 68 VGPR).
// Stream s: K-quarter kq=(s>>3)&3 of groups sgroup, sgroup+1536, ...
// (kq partners differ by blockIdx 8/16/24 -> same XCD -> ea L2 reuse).
// Private hh + private gacc (ds_add_u32 fixed-point). Edge->graph via
// 2 loads + 4 __shfl. Flush: global int atomics into 256 super-slices.
// ---------------------------------------------------------------------------
__global__ __launch_bounds__(64, 3) void edge_kernel(
    const unsigned* __restrict__ xh, const float* __restrict__ ea,
    const int* __restrict__ ei, const int* __restrict__ batch,
    const float* __restrict__ sc, const float* __restrict__ sh,
    const unsigned* __restrict__ Bbuf, const unsigned* __restrict__ Bw1v,
    int* __restrict__ gpartI)
{
  __shared__ unsigned hh[320];   // [channel 16][m 16 pad 20]
  __shared__ int gacc[1280];     // per-graph fixed-point sums (this wave)
  const int lane = threadIdx.x;
  const int nl = lane & 15, q = lane >> 4;
  const int s = blockIdx.x;
  const int kq = (s >> 3) & 3;
  const int sgroup = ((s >> 5) << 3) | (s & 7);   // [0, 1536)
  const int* srcp = ei;
  const int* dstp = ei + E_EDGES;

  for (int v = lane; v < 1280; v += 64) gacc[v] = 0;

  // persistent B fragments (this wave's K-quarter)
  F8U bb[8][2];
#pragma unroll
  for (int sl = 0; sl < 8; ++sl)
#pragma unroll
    for (int nt = 0; nt < 2; ++nt)
      bb[sl][nt].u4 =
          ((const u32x4*)Bbuf)[((kq * 8 + sl) * 2 + nt) * 64 + lane];
  F8U bx[2];
  if (kq == 3) {
    bx[0].u4 = ((const u32x4*)Bbuf)[64 * 64 + lane];
    bx[1].u4 = ((const u32x4*)Bbuf)[65 * 64 + lane];
  } else {
    bx[0].u4 = (u32x4){0u, 0u, 0u, 0u};
    bx[1].u4 = (u32x4){0u, 0u, 0u, 0u};
  }
  F8U bw1; bw1.u4 = ((const u32x4*)Bw1v)[kq * 64 + lane];
  const float scv = sc[kq * 16 + nl];
  const float shv = sh[kq * 16 + nl];
  const int hrb = (q >> 1) * 20 + nl;   // read base: c = 2sl + (q>>1), m = nl
  const int qh = q & 1;

  // ---- prologue: loads for first group ----
  int g = sgroup;
  f32x4 eaA = (f32x4){0.f,0.f,0.f,0.f}, eaB = eaA;
  u32x4 xp = (u32x4){0u,0u,0u,0u};
  int ge = 0;
  {
    int base = g * 16;
    if (q < 2) {
      const float* p = ea + (size_t)(base + nl) * 16 + q * 8;
      eaA = *(const f32x4*)p;
      eaB = *(const f32x4*)(p + 4);
    }
    int src = srcp[base + nl];
    xp = ((const u32x4*)xh)[src * 2 + qh];
    ge = batch[dstp[base + nl]];   // lane nl holds graph of edge nl
  }

  while (g < NGROUPS) {
    const int gn = g + GSTRIDE;

    // ---- h-stage: 16 edges x this wave's 16 channels (1 MFMA) ----
    {
      F8U aEA;
      if (q < 2) {
        aEA.h2[0] = pkrtz(eaA[0], eaA[1]); aEA.h2[1] = pkrtz(eaA[2], eaA[3]);
        aEA.h2[2] = pkrtz(eaB[0], eaB[1]); aEA.h2[3] = pkrtz(eaB[2], eaB[3]);
      } else {
        aEA.u4 = (u32x4){0u, 0u, 0u, 0u};
      }
      f32x4 hD = __builtin_amdgcn_mfma_f32_16x16x32_f16(
          aEA.v, bw1.v, (f32x4){0.f, 0.f, 0.f, 0.f}, 0, 0, 0);
#pragma unroll
      for (int r = 0; r < 4; ++r) {
        float h = fmaxf(hD[r] * scv + shv, 0.f);
        H2U pk; pk.h = pkrtz(h, h);   // packed-duplicated
        hh[nl * 20 + q * 4 + r] = pk.u;   // [c=nl][m=q*4+r]
      }
    }
    F8U xcur; xcur.u4 = xp;
    // edge->graph for this wave's 4 C-rows (ds_bpermute, LDS pipe)
    int gq0 = __shfl(ge, q * 4 + 0, 64);
    int gq1 = __shfl(ge, q * 4 + 1, 64);
    int gq2 = __shfl(ge, q * 4 + 2, 64);
    int gq3 = __shfl(ge, q * 4 + 3, 64);

    // ---- prefetch next group (overlaps K-loop; wave-local vmcnt) ----
    f32x4 eaAn = (f32x4){0.f,0.f,0.f,0.f}, eaBn = eaAn;
    u32x4 xpn = (u32x4){0u,0u,0u,0u};
    int gen = 0;
    if (gn < NGROUPS) {
      int base = gn * 16;
      if (q < 2) {
        const float* p = ea + (size_t)(base + nl) * 16 + q * 8;
        eaAn = *(const f32x4*)p;
        eaBn = *(const f32x4*)(p + 4);
      }
      int src = srcp[base + nl];
      xpn = ((const u32x4*)xh)[src * 2 + qh];
      gen = batch[dstp[base + nl]];
    }

    // ---- K-loop: A[m][k] = h[m][c] * x[m][i], 8 steps x 2 N-tiles ----
    f32x4 acc0 = (f32x4){0.f, 0.f, 0.f, 0.f};
    f32x4 acc1 = (f32x4){0.f, 0.f, 0.f, 0.f};
#pragma unroll
    for (int sl = 0; sl < 8; ++sl) {
      H2U hu; hu.u = hh[hrb + sl * 40];
      F8U av;
      av.h2[0] = hu.h * xcur.h2[0];
      av.h2[1] = hu.h * xcur.h2[1];
      av.h2[2] = hu.h * xcur.h2[2];
      av.h2[3] = hu.h * xcur.h2[3];
      acc0 = __builtin_amdgcn_mfma_f32_16x16x32_f16(av.v, bb[sl][0].v, acc0,
                                                    0, 0, 0);
      acc1 = __builtin_amdgcn_mfma_f32_16x16x32_f16(av.v, bb[sl][1].v, acc1,
                                                    0, 0, 0);
    }
    if (kq == 3) {   // b2 extra K-step: A = x (coefficient-1 trick)
      F8U av;
      if (q < 2) av = xcur;
      else       av.u4 = (u32x4){0u, 0u, 0u, 0u};
      acc0 = __builtin_amdgcn_mfma_f32_16x16x32_f16(av.v, bx[0].v, acc0,
                                                    0, 0, 0);
      acc1 = __builtin_amdgcn_mfma_f32_16x16x32_f16(av.v, bx[1].v, acc1,
                                                    0, 0, 0);
    }

    // ---- fixed-point partials into private gacc (native ds_add_u32) ----
    {
      int gi;
      gi = gq0 * 20;
      atomicAdd(&gacc[gi + nl], __float2int_rn(acc0[0] * QSCALE));
      if (nl < 4) atomicAdd(&gacc[gi + 16 + nl], __float2int_rn(acc1[0] * QSCALE));
      gi = gq1 * 20;
      atomicAdd(&gacc[gi + nl], __float2int_rn(acc0[1] * QSCALE));
      if (nl < 4) atomicAdd(&gacc[gi + 16 + nl], __float2int_rn(acc1[1] * QSCALE));
      gi = gq2 * 20;
      atomicAdd(&gacc[gi + nl], __float2int_rn(acc0[2] * QSCALE));
      if (nl < 4) atomicAdd(&gacc[gi + 16 + nl], __float2int_rn(acc1[2] * QSCALE));
      gi = gq3 * 20;
      atomicAdd(&gacc[gi + nl], __float2int_rn(acc0[3] * QSCALE));
      if (nl < 4) atomicAdd(&gacc[gi + 16 + nl], __float2int_rn(acc1[3] * QSCALE));
    }

    // rotate prefetch -> current
    g = gn;
    eaA = eaAn; eaB = eaBn; xp = xpn; ge = gen;
  }

  // ---- flush: global int atomics into super-slice (24 blocks/slice) ----
  const int ssup = s & (NSUP - 1);
  for (int v = lane; v < 1280; v += 64) {
    int gg = v / 20, o = v - gg * 20;
    atomicAdd(&gpartI[(gg * NSUP + ssup) * 20 + o], gacc[v]);
  }
}

// ---------------------------------------------------------------------------
// critic: block per graph. Exact int reduce of 256 super-slices; pooled =
// (msgsum + sumx@root_w + cnt*bias)/max(cnt,1); 2-layer MLP.
// ---------------------------------------------------------------------------
__global__ __launch_bounds__(256) void critic_kernel(
    const int* __restrict__ gpartI, const float* __restrict__ sumx,
    const float* __restrict__ cntf, const float* __restrict__ root_w,
    const float* __restrict__ bias, const float* __restrict__ a,
    const float* __restrict__ Wc1, const float* __restrict__ bc1,
    const float* __restrict__ Wc2, const float* __restrict__ bc2,
    float* __restrict__ out)
{
  int g = blockIdx.x, t = threadIdx.x;
  __shared__ int part[240];
  __shared__ float pooled[20];
  if (t < 240) {
    int col = t % 20, r = t / 20;  // 12 slice groups
    int s = 0;
    const int* gp = gpartI + (size_t)g * NSUP * 20;
    for (int sl = r; sl < NSUP; sl += 12) s += gp[sl * 20 + col];
    part[t] = s;
  }
  __syncthreads();
  if (t < 20) {
    int si = 0;
#pragma unroll
    for (int r = 0; r < 12; ++r) si += part[r * 20 + t];
    float s = (float)si * QINV;
    float cnt = cntf[g];
    float base = bias[t] * cnt;
#pragma unroll
    for (int i = 0; i < 16; ++i) base += sumx[g * 16 + i] * root_w[i * 20 + t];
    pooled[t] = (s + base) / fmaxf(cnt, 1.f);
  }
  __syncthreads();
  float z = bc1[t];
#pragma unroll
  for (int j = 0; j < 20; ++j) z += pooled[j] * Wc1[j * 256 + t];
#pragma unroll
  for (int j = 0; j < 8; ++j) z += a[g * 8 + j] * Wc1[(20 + j) * 256 + t];
  z = fmaxf(z, 0.f);
  float pr = z * Wc2[t];
#pragma unroll
  for (int off = 32; off >= 1; off >>= 1) pr += __shfl_down(pr, off, 64);
  __shared__ float red[4];
  if ((t & 63) == 0) red[t >> 6] = pr;
  __syncthreads();
  if (t == 0) out[g] = red[0] + red[1] + red[2] + red[3] + bc2[0];
}

// ---------------------------------------------------------------------------
extern "C" void kernel_launch(void* const* d_in, const int* in_sizes, int n_in,
                              void* d_out, int out_size, void* d_ws,
                              size_t ws_size, hipStream_t stream) {
  const float* x         = (const float*)d_in[0];
  const float* edge_attr = (const float*)d_in[1];
  const float* a         = (const float*)d_in[2];
  const int*   ei        = (const int*)d_in[3];
  const int*   batch     = (const int*)d_in[4];
  const float* W1        = (const float*)d_in[5];
  const float* b1        = (const float*)d_in[6];
  const float* gamma     = (const float*)d_in[7];
  const float* beta      = (const float*)d_in[8];
  const float* W2        = (const float*)d_in[9];
  const float* b2        = (const float*)d_in[10];
  const float* root_w    = (const float*)d_in[11];
  const float* bias      = (const float*)d_in[12];
  const float* Wc1       = (const float*)d_in[13];
  const float* bc1       = (const float*)d_in[14];
  const float* Wc2       = (const float*)d_in[15];
  const float* bc2       = (const float*)d_in[16];
  float* out = (float*)d_out;

  // ws layout (floats) — gpartI zeroed via memset, rest fully written
  float* wsf     = (float*)d_ws;
  float* sc      = wsf;                 // 64
  float* sh      = wsf + 64;            // 64
  float* sumx    = wsf + 128;           // 1024
  float* cntf    = wsf + 1152;          // 64
  unsigned* Bw1  = (unsigned*)(wsf + 1216);   // 1024 u32
  unsigned* Bbuf = (unsigned*)(wsf + 2240);   // 16896 u32
  float* gstatsT = wsf + 19136;         // 272*512 = 139264
  unsigned* xhp  = (unsigned*)(wsf + 158400); // N*8 = 400000 u32
  int* gpartI    = (int*)(wsf + 558400);      // 64*256*20 = 327680 ints

  (void)hipMemsetAsync(gpartI, 0, (size_t)G_GRAPHS * NSUP * 20 * sizeof(int),
                       stream);

  const int XCONV_BLOCKS = (N_NODES * 8 + 255) / 256;  // 1563
  setup_kernel<<<STAT_GRID + 70 + XCONV_BLOCKS, 256, 0, stream>>>(
      W2, b2, W1, x, edge_attr, Bbuf, Bw1, xhp, gstatsT);
  mid_kernel<<<G_GRAPHS + 1, 256, 0, stream>>>(gstatsT, W1, b1, gamma, beta,
                                               x, batch, sc, sh, sumx, cntf);
  edge_kernel<<<EDGE_GRID, 64, 0, stream>>>(xhp, edge_attr, ei, batch, sc,
                                            sh, Bbuf, Bw1, gpartI);
  critic_kernel<<<G_GRAPHS, 256, 0, stream>>>(gpartI, sumx, cntf, root_w,
                                              bias, a, Wc1, bc1, Wc2, bc2,
                                              out);
}